// Round 7
// baseline (193.264 us; speedup 1.0000x reference)
//
#include <hip/hip_runtime.h>

// DiffKS fused (R7): R3-verified math, but each wave owns TWO independent
// chunks with ALL loads (22 float4/lane) issued before any compute --
// doubling per-wave outstanding reads to probe the ~3 TB/s read wall.
//   chunk = 256-sample window: 32 warm-up (lanes 0..7) + 224 outputs.
//   scan: d=1,2,4 full affine + d=8 c-only (||P(32)||<=1.5e-5).

#define T_LEN 88200
#define B_N   48
#define OUT_W 224
#define WUP   32
#define NCH   394          // ceil(T_LEN / OUT_W)
#define NQ    (B_N * NCH)  // 18912 chunks
#define WPB   4

__device__ __forceinline__ float4 zero4() { return make_float4(0.f, 0.f, 0.f, 0.f); }

__device__ __forceinline__ float4 ld_g(const float* __restrict__ p, int t) {
    if (t >= 0 && t + 3 < T_LEN) return *(const float4*)(p + t);
    return zero4();
}

struct CD { float4 yv, ae[6], al0, al1, hm1, hm2; int t0; };

__device__ __forceinline__ CD load_chunk(const float* __restrict__ y,
                                         const float* __restrict__ A_exc,
                                         const float* __restrict__ A_loop,
                                         int q, int lane) {
    CD r;
    const int b = q / NCH;
    const int c = q - b * NCH;
    r.t0 = c * OUT_W - WUP + 4 * lane;
    const float* yb  = y      + (size_t)b * T_LEN;
    const float* aeb = A_exc  + (size_t)b * T_LEN * 6;
    const float* alb = A_loop + (size_t)b * T_LEN * 2;
    const int t0 = r.t0;
    if (t0 >= 0 && t0 + 3 < T_LEN) {
        r.yv = *(const float4*)(yb + t0);
        const float4* pa = (const float4*)(aeb + (size_t)t0 * 6);
#pragma unroll
        for (int i = 0; i < 6; ++i) r.ae[i] = pa[i];
        const float4* pl = (const float4*)(alb + (size_t)t0 * 2);
        r.al0 = pl[0]; r.al1 = pl[1];
    } else {
        r.yv = r.al0 = r.al1 = zero4();
#pragma unroll
        for (int i = 0; i < 6; ++i) r.ae[i] = zero4();
    }
    r.hm1 = r.hm2 = zero4();
    if (lane == 0) r.hm1 = ld_g(yb, t0 - 4);
    if (lane <= 1) r.hm2 = ld_g(yb, t0 - 8);
    return r;
}

__device__ __forceinline__ void compute_chunk(const CD& cd, int q, int lane,
                                              float* __restrict__ out) {
    const int b = q / NCH;
    float* ob = out + (size_t)b * T_LEN;
    const int t0 = cd.t0;

    // y history: shuffles of yv, halo loads for lanes 0/1
    float4 hm1, hm2;
    hm1.x = __shfl_up(cd.yv.x, 1, 64); hm1.y = __shfl_up(cd.yv.y, 1, 64);
    hm1.z = __shfl_up(cd.yv.z, 1, 64); hm1.w = __shfl_up(cd.yv.w, 1, 64);
    hm2.x = __shfl_up(cd.yv.x, 2, 64); hm2.y = __shfl_up(cd.yv.y, 2, 64);
    hm2.z = __shfl_up(cd.yv.z, 2, 64); hm2.w = __shfl_up(cd.yv.w, 2, 64);
    if (lane == 0) hm1 = cd.hm1;
    if (lane <= 1) hm2 = cd.hm2;

    const float yw[12] = { hm2.x, hm2.y, hm2.z, hm2.w,
                           hm1.x, hm1.y, hm1.z, hm1.w,
                           cd.yv.x, cd.yv.y, cd.yv.z, cd.yv.w };
    const float* aef = (const float*)cd.ae;
    const float alf[8] = { cd.al0.x, cd.al0.y, cd.al0.z, cd.al0.w,
                           cd.al1.x, cd.al1.y, cd.al1.z, cd.al1.w };

    // ---- FIR + local affine compose over 4 samples ----
    float xs[4], a1s[4], a2s[4];
    float p00 = 1.f, p01 = 0.f, p10 = 0.f, p11 = 1.f, c0 = 0.f, c1 = 0.f;
#pragma unroll
    for (int j = 0; j < 4; ++j) {
        float xv = yw[8 + j];
#pragma unroll
        for (int k = 1; k <= 6; ++k)
            xv = fmaf(aef[j * 6 + (k - 1)], yw[8 + j - k], xv);
        xs[j] = xv;
        const float a1 = alf[2 * j], a2 = alf[2 * j + 1];
        a1s[j] = a1; a2s[j] = a2;
        const float n00 = fmaf(-a1, p00, -a2 * p10);
        const float n01 = fmaf(-a1, p01, -a2 * p11);
        p10 = p00; p11 = p01; p00 = n00; p01 = n01;
        const float nc0 = fmaf(-a1, c0, fmaf(-a2, c1, xv));
        c1 = c0; c0 = nc0;
    }

    // ---- truncated wave scan: d=1,2,4 full; d=8 c-only ----
#pragma unroll
    for (int d = 1; d <= 4; d <<= 1) {
        const float q00 = __shfl_up(p00, d, 64), q01 = __shfl_up(p01, d, 64);
        const float q10 = __shfl_up(p10, d, 64), q11 = __shfl_up(p11, d, 64);
        const float qc0 = __shfl_up(c0, d, 64),  qc1 = __shfl_up(c1, d, 64);
        if (lane >= d) {
            const float m00 = fmaf(p00, q00, p01 * q10);
            const float m01 = fmaf(p00, q01, p01 * q11);
            const float m10 = fmaf(p10, q00, p11 * q10);
            const float m11 = fmaf(p10, q01, p11 * q11);
            const float nc0 = fmaf(p00, qc0, fmaf(p01, qc1, c0));
            const float nc1 = fmaf(p10, qc0, fmaf(p11, qc1, c1));
            p00 = m00; p01 = m01; p10 = m10; p11 = m11; c0 = nc0; c1 = nc1;
        }
    }
    {
        const float qc0 = __shfl_up(c0, 8, 64), qc1 = __shfl_up(c1, 8, 64);
        if (lane >= 8) {
            const float nc0 = fmaf(p00, qc0, fmaf(p01, qc1, c0));
            const float nc1 = fmaf(p10, qc0, fmaf(p11, qc1, c1));
            c0 = nc0; c1 = nc1;
        }
    }

    // ---- exclusive prefix; replay; store ----
    float y1 = __shfl_up(c0, 1, 64);
    float y2 = __shfl_up(c1, 1, 64);
    if (lane == 0) { y1 = 0.f; y2 = 0.f; }
    float ov[4];
#pragma unroll
    for (int j = 0; j < 4; ++j) {
        const float yt = fmaf(-a1s[j], y1, fmaf(-a2s[j], y2, xs[j]));
        y2 = y1; y1 = yt;
        ov[j] = yt;
    }
    if (lane >= WUP / 4 && t0 + 3 < T_LEN)
        *(float4*)(ob + t0) = make_float4(ov[0], ov[1], ov[2], ov[3]);
}

__global__ __launch_bounds__(256, 4) void diffks_kernel(
    const float* __restrict__ y, const float* __restrict__ A_exc,
    const float* __restrict__ A_loop, float* __restrict__ out) {
    const int tid  = threadIdx.x;
    const int widx = tid >> 6;
    const int lane = tid & 63;
    const int w = blockIdx.x * WPB + widx;      // 0..9455 (grid exact)
    const int qa = 2 * w;                       // two independent chunks
    const int qb = 2 * w + 1;

    // Issue ALL loads for both chunks before any compute.
    CD ca = load_chunk(y, A_exc, A_loop, qa, lane);
    CD cb = load_chunk(y, A_exc, A_loop, qb, lane);

    compute_chunk(ca, qa, lane, out);
    compute_chunk(cb, qb, lane, out);
}

extern "C" void kernel_launch(void* const* d_in, const int* in_sizes, int n_in,
                              void* d_out, int out_size, void* d_ws, size_t ws_size,
                              hipStream_t stream) {
    const float* y      = (const float*)d_in[0];
    const float* A_exc  = (const float*)d_in[1];
    const float* A_loop = (const float*)d_in[2];
    float* out = (float*)d_out;

    const int waves = NQ / 2;              // 9456
    const int grid  = waves / WPB;         // 2364 blocks of 4 waves
    diffks_kernel<<<grid, 256, 0, stream>>>(y, A_exc, A_loop, out);
}